// Round 8
// baseline (667.155 us; speedup 1.0000x reference)
//
#include <hip/hip_runtime.h>
#include <math.h>

typedef short short8 __attribute__((ext_vector_type(8)));
typedef float f32x4 __attribute__((ext_vector_type(4)));

#define BB 32
#define CIN 256
#define COUT 256
#define SPD 64
#define SPP 4096
#define SDIM 256

constexpr float LIN_SCALE  = 0.0625f;                 // 1/sqrt(256)
constexpr float CONV_SCALE = 0.020833333333333332f;   // 1/sqrt(2304)
constexpr float EPS = 1e-6f;

// ---- ws byte-offset layout ----
#define WSB_STYLE   0ULL
#define WSB_DEMOD   32768ULL
#define WSB_WSQ     65536ULL
#define WSB_SP      327680ULL
#define WSB_DSP     851968ULL
#define WSB_ZERO    852096ULL      // 1 KiB of zeros
#define WSB_WT2     860160ULL      // 1,179,648 B bf16 weights [tap][co][ci]
#define WSB_SSQP    2039808ULL     // 32,768 B ssq partials [256][32] f32
#define WSB_XST     2097152ULL     // 67,108,864 B bf16 xs_t [b][p][ci]
#define WS_NEED     (WSB_XST + 67108864ULL)

__device__ inline unsigned short f2bf(float f) {
    unsigned u = __builtin_bit_cast(unsigned, f);
    u = (u + 0x7fffu + ((u >> 16) & 1u)) >> 16;   // RNE
    return (unsigned short)u;
}

// async global->LDS DMA, 16B per lane; LDS dest = wave-uniform base + lane*16
__device__ inline void dma16(const void* g, void* l) {
    __builtin_amdgcn_global_load_lds(
        (const __attribute__((address_space(1))) unsigned int*)g,
        (__attribute__((address_space(3))) unsigned int*)l, 16, 0, 0);
}

// ---------------- prep kernels ----------------

__global__ void k_zero(unsigned* __restrict__ p) {
    p[threadIdx.x] = 0u;   // 256 u32 = 1 KiB
}

__global__ void k_wsq(const float* __restrict__ weight, float* __restrict__ wsq) {
    int co = blockIdx.x, ci = threadIdx.x;
    const float* wp = weight + (co * CIN + ci) * 9;
    float s = 0.f;
#pragma unroll
    for (int t = 0; t < 9; t++) { float v = wp[t]; s += v * v; }
    wsq[co * CIN + ci] = s;
}

// style + demod, coalesced: 4 lanes share one row, shfl_xor reduce.
__global__ __launch_bounds__(256) void k_style(
    const float* __restrict__ style_in,
    const float* __restrict__ mod_w,
    const float* __restrict__ mod_b,
    const float* __restrict__ wsq,
    float* __restrict__ style,
    float* __restrict__ demod) {
    __shared__ float s_in[SDIM];
    __shared__ float s2[CIN];
    int b = blockIdx.x, t = threadIdx.x;
    s_in[t] = style_in[b * 512 + t];
    __syncthreads();
    int kq = t & 3, rr = t >> 2;   // rr 0..63
#pragma unroll
    for (int c = 0; c < 4; c++) {
        int ci = c * 64 + rr;
        const float4* wrow = (const float4*)(mod_w + (size_t)ci * 256 + kq * 64);
        float a = 0.f;
#pragma unroll
        for (int j = 0; j < 16; j++) {
            float4 wv = wrow[j];
            int kb = kq * 64 + j * 4;
            a += s_in[kb] * wv.x + s_in[kb + 1] * wv.y + s_in[kb + 2] * wv.z + s_in[kb + 3] * wv.w;
        }
        a += __shfl_xor(a, 1); a += __shfl_xor(a, 2);
        if (kq == 0) {
            float st = a * LIN_SCALE + mod_b[ci];
            style[b * 256 + ci] = st;
            s2[ci] = st * st;
        }
    }
    __syncthreads();
#pragma unroll
    for (int c = 0; c < 4; c++) {
        int co = c * 64 + rr;
        const float4* wrow = (const float4*)(wsq + (size_t)co * 256 + kq * 64);
        float a = 0.f;
#pragma unroll
        for (int j = 0; j < 16; j++) {
            float4 wv = wrow[j];
            int kb = kq * 64 + j * 4;
            a += s2[kb] * wv.x + s2[kb + 1] * wv.y + s2[kb + 2] * wv.z + s2[kb + 3] * wv.w;
        }
        a += __shfl_xor(a, 1); a += __shfl_xor(a, 2);
        if (kq == 0) demod[b * 256 + co] = rsqrtf(CONV_SCALE * CONV_SCALE * a + EPS);
    }
}

// spatial map, parallel: 256 blocks x 16 p-rows; lanes share sp_w rows
// (broadcast); deterministic per-block partial sums (no atomics).
__global__ __launch_bounds__(256) void k_spatial2(
    const float* __restrict__ style_in,
    const float* __restrict__ sp_w,
    const float* __restrict__ sp_b,
    float* __restrict__ sp,
    float* __restrict__ ssq_part) {
    __shared__ float s_in[32][257];
    __shared__ float sred[256];
    int blk = blockIdx.x, t = threadIdx.x;
    int p0 = blk * 16;
    for (int idx = t; idx < 8192; idx += 256) {
        int b = idx >> 8, k = idx & 255;
        s_in[b][k] = style_in[b * 512 + 256 + k];
    }
    __syncthreads();
    int b = t & 31, pl = t >> 5;      // pl 0..7
    float ss = 0.f;
#pragma unroll
    for (int half = 0; half < 2; half++) {
        int p = p0 + half * 8 + pl;
        const float* wr = sp_w + (size_t)p * 256;
        float a = 0.f;
        for (int k = 0; k < 256; k++) a += s_in[b][k] * wr[k];
        float v = a * LIN_SCALE + sp_b[p];
        sp[b * SPP + p] = v;
        ss += v * v;
    }
    sred[t] = ss;
    __syncthreads();
    if (t < 32) {
        float s = 0.f;
#pragma unroll
        for (int r = 0; r < 8; r++) s += sred[r * 32 + t];
        ssq_part[blk * 32 + t] = s;
    }
}

__global__ void k_dsp(const float* __restrict__ ssq_part, float* __restrict__ dsp) {
    int b = threadIdx.x;   // 32 threads
    float s = 0.f;
    for (int i = 0; i < 256; i++) s += ssq_part[i * 32 + b];
    dsp[b] = sqrtf((float)SPP / s + EPS);
}

// weight [co][ci][tap] fp32 -> wt2[tap][co][ci] bf16 (raw, unscaled)
__global__ void k_wt(const float* __restrict__ weight, unsigned short* __restrict__ wt2) {
    int idx = blockIdx.x * 256 + threadIdx.x;   // grid 2304 -> 589824
    int tap = idx >> 16;
    int r = idx & 65535;
    int co = r >> 8, ci = r & 255;
    wt2[idx] = f2bf(weight[(co * 256 + ci) * 9 + tap]);
}

// x [b][ci][p] fp32 -> xs_t[b][p][ci] bf16 scaled by style[b][ci].
// LDS-tiled transpose, coalesced both sides.
__global__ __launch_bounds__(256) void k_xt(
    const float* __restrict__ x, const float* __restrict__ style,
    unsigned short* __restrict__ xst) {
    __shared__ float tile[64][65];
    int bid = blockIdx.x;
    int b  = (bid & 7) * 4 + ((bid >> 3) & 3);
    int p0 = (bid >> 5) * 64;
    int t = threadIdx.x;
    int w = t >> 6, lane = t & 63;
    int hi = t >> 5, lo = t & 31;

    for (int cc = 0; cc < 4; cc++) {
#pragma unroll
        for (int it = 0; it < 16; it++) {
            int ci_l = it * 4 + w;
            int ci = cc * 64 + ci_l;
            float st = style[b * 256 + ci];
            tile[lane][ci_l] = x[((size_t)(b * 256 + ci)) * SPP + p0 + lane] * st;
        }
        __syncthreads();
#pragma unroll
        for (int it = 0; it < 8; it++) {
            int p_l = it * 8 + hi;
            unsigned pk = (unsigned)f2bf(tile[p_l][lo * 2])
                        | ((unsigned)f2bf(tile[p_l][lo * 2 + 1]) << 16);
            unsigned* dst = (unsigned*)xst + ((size_t)(b * SPP + p0 + p_l)) * 128 + cc * 32 + lo;
            *dst = pk;
        }
        __syncthreads();
    }
}

// ---------------- MFMA conv kernel: phase-staged, barrier-free kc loop ----
// grid 1024: bid -> [rt(5)][b_lo(2)][xcd(3)], b = xcd*4+b_lo, h0 = rt*2
// block 256 = 4 waves; wave w owns co slab [w*64, w*64+64) x 128 p (2 rows).
// The block's WHOLE x-tile (264 slots = 4 rows x 66 cols) is staged in two
// ci-halves of 66 KB. Each half: 264 slots x 256 B (128 ci bf16), swizzled
// byte ^= (slot&15)<<4 (involution; DMA writes linear dest from
// inverse-swizzled global src; ds_read applies the same XOR).
// kc loop has NO barriers and NO DMA -> no synchronized vmcnt(0) drains;
// compiler pipelines register-dest weight loads across a 36-tap window.

__device__ inline void stage_unit(int u, int h, const unsigned short* __restrict__ xb,
                                  const unsigned short* __restrict__ zeropad,
                                  char* stg, int h0) {
    int slot = u >> 4, u16 = u & 15;
    int tu = u16 ^ (slot & 15);            // inverse swizzle on source
    int row = slot / 66, col = slot - row * 66;
    int gh = h0 + row - 1, gw = col - 1;
    const unsigned short* s = zeropad;
    if ((unsigned)gh < 64u && (unsigned)gw < 64u)
        s = xb + ((size_t)(gh * 64 + gw)) * 256 + h * 128 + tu * 8;
    dma16(s, stg + (size_t)u * 16);
}

__global__ __launch_bounds__(256, 2) void k_conv_mfma(
    const unsigned short* __restrict__ xst,
    const unsigned short* __restrict__ wt2,
    const float* __restrict__ demod,
    const float* __restrict__ sp,
    const float* __restrict__ dsp,
    const unsigned short* __restrict__ zeropad,
    float* __restrict__ out)
{
    __shared__ union {
        char stage[67584];         // 264 slots x 256 B (one ci-half)
        float ep[4][2176];         // 4 waves x 32 rows x 68 floats (34816 B)
    } lds;
    __shared__ float demod_l[256];

    int bid = blockIdx.x;
    int b  = (bid & 7) * 4 + ((bid >> 3) & 3);
    int rt = bid >> 5;
    int h0 = rt * 2;
    int t = threadIdx.x;
    int w = t >> 6, lane = t & 63;
    int lcol = lane & 15, kg = lane >> 4;

    demod_l[t] = demod[b * 256 + t];

    const unsigned short* xb = xst + (size_t)b * SPP * 256;

    // 4224 16B-units per half: 16 full rounds + 128-unit tail (waves 0,1)
#define STAGE(H) { _Pragma("unroll") \
    for (int it = 0; it < 16; it++) stage_unit(t + it * 256, (H), xb, zeropad, lds.stage, h0); \
    if (t < 128) stage_unit(t + 4096, (H), xb, zeropad, lds.stage, h0); }

    STAGE(0);

    f32x4 acc[4][8];
#pragma unroll
    for (int m = 0; m < 4; m++)
#pragma unroll
        for (int n = 0; n < 8; n++) acc[m][n] = (f32x4){0.f, 0.f, 0.f, 0.f};

    const unsigned short* wbase = wt2 + (size_t)(w * 64 + lcol) * 256 + kg * 8;
    __syncthreads();   // drain prologue DMA (vmcnt(0) once)

#pragma unroll
    for (int h = 0; h < 2; h++) {
        if (h) {
            __syncthreads();   // all waves done reading half 0
            STAGE(1);
            __syncthreads();   // drain DMA for half 1
        }
#pragma unroll
        for (int kcl = 0; kcl < 4; kcl++) {
            int kc = h * 4 + kcl;
            const unsigned short* wk = wbase + kc * 32;
            short8 wA[4], wB[4];
#pragma unroll
            for (int m = 0; m < 4; m++) wA[m] = *(const short8*)(wk + m * 4096);
#pragma unroll
            for (int tap = 0; tap < 9; tap++) {
                const int dh = tap / 3, dw = tap - dh * 3;
                if (tap < 8) {
                    const unsigned short* wn = wk + (tap + 1) * 65536;
#pragma unroll
                    for (int m = 0; m < 4; m++) wB[m] = *(const short8*)(wn + m * 4096);
                }
#pragma unroll
                for (int n = 0; n < 8; n++) {
                    int slot = (dh + (n >> 2)) * 66 + dw + (n & 3) * 16 + lcol;
                    int off = slot * 256 + ((kcl * 64 + kg * 16) ^ ((slot & 15) << 4));
                    short8 bv = *(const short8*)(lds.stage + off);
                    acc[0][n] = __builtin_amdgcn_mfma_f32_16x16x32_bf16(wA[0], bv, acc[0][n], 0, 0, 0);
                    acc[1][n] = __builtin_amdgcn_mfma_f32_16x16x32_bf16(wA[1], bv, acc[1][n], 0, 0, 0);
                    acc[2][n] = __builtin_amdgcn_mfma_f32_16x16x32_bf16(wA[2], bv, acc[2][n], 0, 0, 0);
                    acc[3][n] = __builtin_amdgcn_mfma_f32_16x16x32_bf16(wA[3], bv, acc[3][n], 0, 0, 0);
                }
#pragma unroll
                for (int m = 0; m < 4; m++) wA[m] = wB[m];
            }
        }
    }
    __syncthreads();   // x-tile dead; safe to reuse LDS as epilogue buffer

    // ---- epilogue: scale, per-wave LDS transpose, coalesced dwordx4 stores ----
    float dspb = dsp[b];
    float spn[2][4];
#pragma unroll
    for (int rh = 0; rh < 2; rh++)
#pragma unroll
        for (int nn = 0; nn < 4; nn++)
            spn[rh][nn] = sp[b * SPP + (h0 + rh) * 64 + nn * 16 + lcol] * dspb;

    float* ep = &lds.ep[w][0];
#pragma unroll
    for (int rh = 0; rh < 2; rh++) {
#pragma unroll
        for (int ch = 0; ch < 2; ch++) {
#pragma unroll
            for (int mm = 0; mm < 2; mm++) {
#pragma unroll
                for (int r2 = 0; r2 < 4; r2++) {
                    int lr = mm * 16 + kg * 4 + r2;
                    float dm = demod_l[w * 64 + ch * 32 + lr] * CONV_SCALE;
#pragma unroll
                    for (int nn = 0; nn < 4; nn++)
                        ep[lr * 68 + nn * 16 + lcol] =
                            acc[ch * 2 + mm][rh * 4 + nn][r2] * dm * spn[rh][nn];
                }
            }
            __syncthreads();
#pragma unroll
            for (int i = 0; i < 8; i++) {
                int lr = i * 4 + kg;
                f32x4 v = *(const f32x4*)(ep + lr * 68 + lcol * 4);
                int co_g = w * 64 + ch * 32 + lr;
                *(f32x4*)&out[((size_t)(b * 256 + co_g)) * SPP + (h0 + rh) * 64 + lcol * 4] = v;
            }
            __syncthreads();
        }
    }
}

// ---------------- legacy spatial (fallback path only) ----------------
__global__ void k_spatial(const float* __restrict__ style_in,
                          const float* __restrict__ sp_w,
                          const float* __restrict__ sp_b,
                          float* __restrict__ sp,
                          float* __restrict__ dsp) {
    __shared__ float s_in[SDIM];
    __shared__ float red[256];
    int b = blockIdx.x, t = threadIdx.x;
    s_in[t] = style_in[b * 512 + 256 + t];
    __syncthreads();
    float ss = 0.f;
    for (int i = 0; i < 16; i++) {
        int p = i * 256 + t;
        const float* wr = sp_w + p * SDIM;
        float acc = 0.f;
        for (int k = 0; k < 256; k++) acc += s_in[k] * wr[k];
        float v = acc * LIN_SCALE + sp_b[p];
        sp[b * SPP + p] = v;
        ss += v * v;
    }
    red[t] = ss; __syncthreads();
    for (int o = 128; o > 0; o >>= 1) { if (t < o) red[t] += red[t + o]; __syncthreads(); }
    if (t == 0) dsp[b] = sqrtf((float)SPP / red[0] + EPS);
}

// ---------------- fp32 fallback conv (round-1, known-good) ----------------

#define COTILE 16
#define TS 32
#define HALO 34
#define XS 36

__global__ __launch_bounds__(256) void k_conv_f32(
    const float* __restrict__ x, const float* __restrict__ weight,
    const float* __restrict__ style, const float* __restrict__ demod,
    const float* __restrict__ sp, const float* __restrict__ dsp,
    float* __restrict__ out) {
    __shared__ float xt[HALO * XS];
    __shared__ float wl[COTILE * 12];
    __shared__ float dml[COTILE];

    int bid = blockIdx.x;
    int tile = bid & 3;
    int cot = (bid >> 2) & 15;
    int b = bid >> 6;
    int h0 = (tile >> 1) * TS, w0 = (tile & 1) * TS;
    int t = threadIdx.x;
    int r = t >> 3;
    int cb = (t & 7) * 4;

    if (t < COTILE) dml[t] = demod[b * COUT + cot * COTILE + t];

    float acc[COTILE][4];
#pragma unroll
    for (int co = 0; co < COTILE; co++)
#pragma unroll
        for (int c = 0; c < 4; c++) acc[co][c] = 0.f;

    const float* xb = x + (size_t)b * CIN * SPP;
    const float* stb = style + b * CIN;

    for (int ci = 0; ci < CIN; ci++) {
        __syncthreads();
        const float* xc = xb + ci * SPP;
        for (int idx = t; idx < HALO * HALO; idx += 256) {
            int i = idx / HALO, j = idx - i * HALO;
            int h = h0 + i - 1, wv2 = w0 + j - 1;
            float v = 0.f;
            if ((unsigned)h < SPD && (unsigned)wv2 < SPD) v = xc[h * SPD + wv2];
            xt[i * XS + j] = v;
        }
        if (t < COTILE * 9) {
            int co = t / 9, tap = t - co * 9;
            float wv = weight[((cot * COTILE + co) * CIN + ci) * 9 + tap];
            wl[co * 12 + tap] = wv * (CONV_SCALE * stb[ci]) * dml[co];
        }
        __syncthreads();

        float xv[3][6];
#pragma unroll
        for (int dh = 0; dh < 3; dh++)
#pragma unroll
            for (int jj = 0; jj < 6; jj++)
                xv[dh][jj] = xt[(r + dh) * XS + cb + jj];

#pragma unroll
        for (int co = 0; co < COTILE; co++) {
            float w9[9];
#pragma unroll
            for (int q = 0; q < 9; q++) w9[q] = wl[co * 12 + q];
#pragma unroll
            for (int c = 0; c < 4; c++) {
                float a = acc[co][c];
#pragma unroll
                for (int dh = 0; dh < 3; dh++)
#pragma unroll
                    for (int dw = 0; dw < 3; dw++)
                        a += w9[dh * 3 + dw] * xv[dh][c + dw];
                acc[co][c] = a;
            }
        }
    }

    float dspb = dsp[b];
    int hh = h0 + r, ww = w0 + cb;
    const float* spb = sp + b * SPP + hh * SPD + ww;
    float m[4];
#pragma unroll
    for (int c = 0; c < 4; c++) m[c] = spb[c] * dspb;
#pragma unroll
    for (int co = 0; co < COTILE; co++) {
        float4 v = make_float4(acc[co][0] * m[0], acc[co][1] * m[1],
                               acc[co][2] * m[2], acc[co][3] * m[3]);
        *(float4*)&out[(size_t)((b * COUT + cot * COTILE + co) * SPP) + hh * SPD + ww] = v;
    }
}

// ---------------- launcher ----------------

extern "C" void kernel_launch(void* const* d_in, const int* in_sizes, int n_in,
                              void* d_out, int out_size, void* d_ws, size_t ws_size,
                              hipStream_t stream) {
    const float* x        = (const float*)d_in[0];
    const float* style_in = (const float*)d_in[1];
    const float* weight   = (const float*)d_in[2];
    const float* mod_w    = (const float*)d_in[3];
    const float* mod_b    = (const float*)d_in[4];
    const float* sp_w     = (const float*)d_in[5];
    const float* sp_b     = (const float*)d_in[6];
    float* out = (float*)d_out;
    char* wsb = (char*)d_ws;

    float* style = (float*)(wsb + WSB_STYLE);
    float* demod = (float*)(wsb + WSB_DEMOD);
    float* wsq   = (float*)(wsb + WSB_WSQ);
    float* sp    = (float*)(wsb + WSB_SP);
    float* dsp   = (float*)(wsb + WSB_DSP);
    float* ssqp  = (float*)(wsb + WSB_SSQP);
    unsigned short* wt2 = (unsigned short*)(wsb + WSB_WT2);
    unsigned short* xst = (unsigned short*)(wsb + WSB_XST);

    hipLaunchKernelGGL(k_zero, dim3(1), dim3(256), 0, stream, (unsigned*)(wsb + WSB_ZERO));
    hipLaunchKernelGGL(k_wsq, dim3(COUT), dim3(CIN), 0, stream, weight, wsq);
    hipLaunchKernelGGL(k_style, dim3(BB), dim3(256), 0, stream,
                       style_in, mod_w, mod_b, wsq, style, demod);

    if (ws_size >= WS_NEED) {
        hipLaunchKernelGGL(k_spatial2, dim3(256), dim3(256), 0, stream,
                           style_in, sp_w, sp_b, sp, ssqp);
        hipLaunchKernelGGL(k_dsp, dim3(1), dim3(32), 0, stream, ssqp, dsp);
        hipLaunchKernelGGL(k_wt, dim3(2304), dim3(256), 0, stream, weight, wt2);
        hipLaunchKernelGGL(k_xt, dim3(2048), dim3(256), 0, stream, x, style, xst);
        hipLaunchKernelGGL(k_conv_mfma, dim3(1024), dim3(256), 0, stream,
                           xst, wt2, demod, sp, dsp,
                           (const unsigned short*)(wsb + WSB_ZERO), out);
    } else {
        hipLaunchKernelGGL(k_spatial, dim3(BB), dim3(256), 0, stream,
                           style_in, sp_w, sp_b, sp, dsp);
        hipLaunchKernelGGL(k_conv_f32, dim3(2048), dim3(256), 0, stream,
                           x, weight, style, demod, sp, dsp, out);
    }
}

// Round 9
// 608.477 us; speedup vs baseline: 1.0964x; 1.0964x over previous
//
#include <hip/hip_runtime.h>
#include <math.h>

typedef short short8 __attribute__((ext_vector_type(8)));
typedef float f32x4 __attribute__((ext_vector_type(4)));

#define BB 32
#define CIN 256
#define COUT 256
#define SPD 64
#define SPP 4096
#define SDIM 256

constexpr float LIN_SCALE  = 0.0625f;                 // 1/sqrt(256)
constexpr float CONV_SCALE = 0.020833333333333332f;   // 1/sqrt(2304)
constexpr float EPS = 1e-6f;

// ---- ws byte-offset layout ----
#define WSB_STYLE   0ULL
#define WSB_DEMOD   32768ULL
#define WSB_WSQ     65536ULL
#define WSB_SP      327680ULL
#define WSB_DSP     851968ULL
#define WSB_ZERO    852096ULL      // 1 KiB of zeros
#define WSB_WT2     860160ULL      // 1,179,648 B bf16 weights [tap][co][ci]
#define WSB_SSQP    2039808ULL     // 32,768 B ssq partials [256][32] f32
#define WSB_XST     2097152ULL     // 67,108,864 B bf16 xs_t [b][p][ci]
#define WS_NEED     (WSB_XST + 67108864ULL)

__device__ inline unsigned short f2bf(float f) {
    unsigned u = __builtin_bit_cast(unsigned, f);
    u = (u + 0x7fffu + ((u >> 16) & 1u)) >> 16;   // RNE
    return (unsigned short)u;
}

// async global->LDS DMA, 16B per lane; LDS dest = wave-uniform base + lane*16
__device__ inline void dma16(const void* g, void* l) {
    __builtin_amdgcn_global_load_lds(
        (const __attribute__((address_space(1))) unsigned int*)g,
        (__attribute__((address_space(3))) unsigned int*)l, 16, 0, 0);
}

// ---------------- prep kernels ----------------

__global__ void k_zero(unsigned* __restrict__ p) {
    p[threadIdx.x] = 0u;   // 256 u32 = 1 KiB
}

__global__ void k_wsq(const float* __restrict__ weight, float* __restrict__ wsq) {
    int co = blockIdx.x, ci = threadIdx.x;
    const float* wp = weight + (co * CIN + ci) * 9;
    float s = 0.f;
#pragma unroll
    for (int t = 0; t < 9; t++) { float v = wp[t]; s += v * v; }
    wsq[co * CIN + ci] = s;
}

// style + demod, coalesced: 4 lanes share one row, shfl_xor reduce.
__global__ __launch_bounds__(256) void k_style(
    const float* __restrict__ style_in,
    const float* __restrict__ mod_w,
    const float* __restrict__ mod_b,
    const float* __restrict__ wsq,
    float* __restrict__ style,
    float* __restrict__ demod) {
    __shared__ float s_in[SDIM];
    __shared__ float s2[CIN];
    int b = blockIdx.x, t = threadIdx.x;
    s_in[t] = style_in[b * 512 + t];
    __syncthreads();
    int kq = t & 3, rr = t >> 2;   // rr 0..63
#pragma unroll
    for (int c = 0; c < 4; c++) {
        int ci = c * 64 + rr;
        const float4* wrow = (const float4*)(mod_w + (size_t)ci * 256 + kq * 64);
        float a = 0.f;
#pragma unroll
        for (int j = 0; j < 16; j++) {
            float4 wv = wrow[j];
            int kb = kq * 64 + j * 4;
            a += s_in[kb] * wv.x + s_in[kb + 1] * wv.y + s_in[kb + 2] * wv.z + s_in[kb + 3] * wv.w;
        }
        a += __shfl_xor(a, 1); a += __shfl_xor(a, 2);
        if (kq == 0) {
            float st = a * LIN_SCALE + mod_b[ci];
            style[b * 256 + ci] = st;
            s2[ci] = st * st;
        }
    }
    __syncthreads();
#pragma unroll
    for (int c = 0; c < 4; c++) {
        int co = c * 64 + rr;
        const float4* wrow = (const float4*)(wsq + (size_t)co * 256 + kq * 64);
        float a = 0.f;
#pragma unroll
        for (int j = 0; j < 16; j++) {
            float4 wv = wrow[j];
            int kb = kq * 64 + j * 4;
            a += s2[kb] * wv.x + s2[kb + 1] * wv.y + s2[kb + 2] * wv.z + s2[kb + 3] * wv.w;
        }
        a += __shfl_xor(a, 1); a += __shfl_xor(a, 2);
        if (kq == 0) demod[b * 256 + co] = rsqrtf(CONV_SCALE * CONV_SCALE * a + EPS);
    }
}

// spatial map, parallel: 256 blocks x 16 p-rows; lanes share sp_w rows
// (broadcast); deterministic per-block partial sums (no atomics).
__global__ __launch_bounds__(256) void k_spatial2(
    const float* __restrict__ style_in,
    const float* __restrict__ sp_w,
    const float* __restrict__ sp_b,
    float* __restrict__ sp,
    float* __restrict__ ssq_part) {
    __shared__ float s_in[32][257];
    __shared__ float sred[256];
    int blk = blockIdx.x, t = threadIdx.x;
    int p0 = blk * 16;
    for (int idx = t; idx < 8192; idx += 256) {
        int b = idx >> 8, k = idx & 255;
        s_in[b][k] = style_in[b * 512 + 256 + k];
    }
    __syncthreads();
    int b = t & 31, pl = t >> 5;      // pl 0..7
    float ss = 0.f;
#pragma unroll
    for (int half = 0; half < 2; half++) {
        int p = p0 + half * 8 + pl;
        const float* wr = sp_w + (size_t)p * 256;
        float a = 0.f;
        for (int k = 0; k < 256; k++) a += s_in[b][k] * wr[k];
        float v = a * LIN_SCALE + sp_b[p];
        sp[b * SPP + p] = v;
        ss += v * v;
    }
    sred[t] = ss;
    __syncthreads();
    if (t < 32) {
        float s = 0.f;
#pragma unroll
        for (int r = 0; r < 8; r++) s += sred[r * 32 + t];
        ssq_part[blk * 32 + t] = s;
    }
}

__global__ void k_dsp(const float* __restrict__ ssq_part, float* __restrict__ dsp) {
    int b = threadIdx.x;   // 32 threads
    float s = 0.f;
    for (int i = 0; i < 256; i++) s += ssq_part[i * 32 + b];
    dsp[b] = sqrtf((float)SPP / s + EPS);
}

// weight [co][ci][tap] fp32 -> wt2[tap][co][ci] bf16 (raw, unscaled)
__global__ void k_wt(const float* __restrict__ weight, unsigned short* __restrict__ wt2) {
    int idx = blockIdx.x * 256 + threadIdx.x;   // grid 2304 -> 589824
    int tap = idx >> 16;
    int r = idx & 65535;
    int co = r >> 8, ci = r & 255;
    wt2[idx] = f2bf(weight[(co * 256 + ci) * 9 + tap]);
}

// x [b][ci][p] fp32 -> xs_t[b][p][ci] bf16 scaled by style[b][ci].
// LDS-tiled transpose, coalesced both sides.
__global__ __launch_bounds__(256) void k_xt(
    const float* __restrict__ x, const float* __restrict__ style,
    unsigned short* __restrict__ xst) {
    __shared__ float tile[64][65];
    int bid = blockIdx.x;
    int b  = (bid & 7) * 4 + ((bid >> 3) & 3);
    int p0 = (bid >> 5) * 64;
    int t = threadIdx.x;
    int w = t >> 6, lane = t & 63;
    int hi = t >> 5, lo = t & 31;

    for (int cc = 0; cc < 4; cc++) {
#pragma unroll
        for (int it = 0; it < 16; it++) {
            int ci_l = it * 4 + w;
            int ci = cc * 64 + ci_l;
            float st = style[b * 256 + ci];
            tile[lane][ci_l] = x[((size_t)(b * 256 + ci)) * SPP + p0 + lane] * st;
        }
        __syncthreads();
#pragma unroll
        for (int it = 0; it < 8; it++) {
            int p_l = it * 8 + hi;
            unsigned pk = (unsigned)f2bf(tile[p_l][lo * 2])
                        | ((unsigned)f2bf(tile[p_l][lo * 2 + 1]) << 16);
            unsigned* dst = (unsigned*)xst + ((size_t)(b * SPP + p0 + p_l)) * 128 + cc * 32 + lo;
            *dst = pk;
        }
        __syncthreads();
    }
}

// ---------------- MFMA conv kernel: producer/consumer wave split ----------
// grid 1024: bid -> [rt(5)][b_lo(2)][xcd(3)], b = xcd*4+b_lo, h0 = rt*2
// block 320 = 5 waves: waves 0-3 consume (wave w owns co slab w*64..w*64+64
// x 128 p), wave 4 produces (issues ALL global_load_lds x-staging).
// Rationale: vmcnt is per-wave & in-order. With a dedicated producer, the
// consumers' vmcnt queues hold ONLY their weight loads, so per-tap counted
// waits never drain HBM-latency DMAs. The producer's mandatory vmcnt(0)
// before each barrier overlaps the consumers' ~1500-cyc tap loop.
// LDS x-tile per K-chunk: 264 slots (4 rows x 66 cols) x 64B (32 ci bf16),
// same layout/swizzle as round 6 (measured conflict-clean).

__device__ inline void produce(int kc, char* dst,
                               const unsigned short* __restrict__ xb,
                               const unsigned short* __restrict__ zeropad,
                               int h0, int lane) {
#pragma unroll
    for (int i = 0; i < 17; i++) {        // 1056 16B-units = 16.5 rounds
        if (i < 16 || lane < 32) {
            int u = lane + i * 64;
            int slot = u >> 2, j = u & 3;
            int row = slot / 66, col = slot - row * 66;
            int g = j ^ ((slot >> 1) & 3);     // inverse swizzle on source
            int gh = h0 + row - 1, gw = col - 1;
            const unsigned short* s = zeropad;
            if ((unsigned)gh < 64u && (unsigned)gw < 64u)
                s = xb + ((size_t)(gh * 64 + gw)) * 256 + kc * 32 + g * 8;
            dma16(s, dst + (size_t)u * 16);
        }
    }
}

__global__ __launch_bounds__(320, 2) void k_conv_mfma(
    const unsigned short* __restrict__ xst,
    const unsigned short* __restrict__ wt2,
    const float* __restrict__ demod,
    const float* __restrict__ sp,
    const float* __restrict__ dsp,
    const unsigned short* __restrict__ zeropad,
    float* __restrict__ out)
{
    __shared__ union {
        char stage[2][16896];      // 2 x 264 slots x 64B
        float ep[4][2176];         // 4 waves x 32 rows x 68 floats (34816 B)
    } lds;
    __shared__ float demod_l[256];

    int bid = blockIdx.x;
    int b  = (bid & 7) * 4 + ((bid >> 3) & 3);
    int rt = bid >> 5;
    int h0 = rt * 2;
    int t = threadIdx.x;
    int w = t >> 6, lane = t & 63;
    int lcol = lane & 15, kg = lane >> 4;
    bool producer = (w == 4);

    if (t < 256) demod_l[t] = demod[b * 256 + t];

    const unsigned short* xb = xst + (size_t)b * SPP * 256;

    if (producer) produce(0, &lds.stage[0][0], xb, zeropad, h0, lane);

    f32x4 acc[4][8];
#pragma unroll
    for (int m = 0; m < 4; m++)
#pragma unroll
        for (int n = 0; n < 8; n++) acc[m][n] = (f32x4){0.f, 0.f, 0.f, 0.f};

    const unsigned short* wbase = wt2 + (size_t)((w & 3) * 64 + lcol) * 256 + kg * 8;
    int cur = 0;
    __syncthreads();   // producer drains prologue DMA; consumers free

    for (int kc = 0; kc < 8; kc++) {
        if (producer) {
            if (kc < 7) produce(kc + 1, &lds.stage[cur ^ 1][0], xb, zeropad, h0, lane);
        } else {
            const char* lb = &lds.stage[cur][0];
            const unsigned short* wk = wbase + kc * 32;
            short8 wA[4], wB[4];
#pragma unroll
            for (int m = 0; m < 4; m++) wA[m] = *(const short8*)(wk + m * 4096);
#pragma unroll
            for (int tap = 0; tap < 9; tap++) {
                const int dh = tap / 3, dw = tap - dh * 3;
                if (tap < 8) {
                    const unsigned short* wn = wk + (tap + 1) * 65536;
#pragma unroll
                    for (int m = 0; m < 4; m++) wB[m] = *(const short8*)(wn + m * 4096);
                }
#pragma unroll
                for (int n = 0; n < 8; n++) {
                    int slot = (dh + (n >> 2)) * 66 + dw + (n & 3) * 16 + lcol;
                    int q = (slot >> 1) & 3;
                    short8 bv = *(const short8*)(lb + slot * 64 + ((kg ^ q) << 4));
                    acc[0][n] = __builtin_amdgcn_mfma_f32_16x16x32_bf16(wA[0], bv, acc[0][n], 0, 0, 0);
                    acc[1][n] = __builtin_amdgcn_mfma_f32_16x16x32_bf16(wA[1], bv, acc[1][n], 0, 0, 0);
                    acc[2][n] = __builtin_amdgcn_mfma_f32_16x16x32_bf16(wA[2], bv, acc[2][n], 0, 0, 0);
                    acc[3][n] = __builtin_amdgcn_mfma_f32_16x16x32_bf16(wA[3], bv, acc[3][n], 0, 0, 0);
                }
#pragma unroll
                for (int m = 0; m < 4; m++) wA[m] = wB[m];
            }
        }
        __syncthreads();   // consumers: vmcnt already 0 (all weights consumed);
                           // producer: drains its DMAs (overlapped w/ tap loop)
        cur ^= 1;
    }

    // ---- epilogue: scale, per-wave LDS transpose, coalesced dwordx4 stores ----
    // producer executes the barriers only (uniform barrier count).
    float dspb = dsp[b];
    float spn[2][4];
#pragma unroll
    for (int rh = 0; rh < 2; rh++)
#pragma unroll
        for (int nn = 0; nn < 4; nn++)
            spn[rh][nn] = sp[b * SPP + (h0 + rh) * 64 + nn * 16 + lcol] * dspb;

#pragma unroll
    for (int rh = 0; rh < 2; rh++) {
#pragma unroll
        for (int ch = 0; ch < 2; ch++) {
            if (!producer) {
                float* ep = &lds.ep[w][0];
#pragma unroll
                for (int mm = 0; mm < 2; mm++) {
#pragma unroll
                    for (int r2 = 0; r2 < 4; r2++) {
                        int lr = mm * 16 + kg * 4 + r2;
                        float dm = demod_l[w * 64 + ch * 32 + lr] * CONV_SCALE;
#pragma unroll
                        for (int nn = 0; nn < 4; nn++)
                            ep[lr * 68 + nn * 16 + lcol] =
                                acc[ch * 2 + mm][rh * 4 + nn][r2] * dm * spn[rh][nn];
                    }
                }
            }
            __syncthreads();
            if (!producer) {
                float* ep = &lds.ep[w][0];
#pragma unroll
                for (int i = 0; i < 8; i++) {
                    int lr = i * 4 + kg;
                    f32x4 v = *(const f32x4*)(ep + lr * 68 + lcol * 4);
                    int co_g = w * 64 + ch * 32 + lr;
                    *(f32x4*)&out[((size_t)(b * 256 + co_g)) * SPP + (h0 + rh) * 64 + lcol * 4] = v;
                }
            }
            __syncthreads();
        }
    }
}

// ---------------- legacy spatial (fallback path only) ----------------
__global__ void k_spatial(const float* __restrict__ style_in,
                          const float* __restrict__ sp_w,
                          const float* __restrict__ sp_b,
                          float* __restrict__ sp,
                          float* __restrict__ dsp) {
    __shared__ float s_in[SDIM];
    __shared__ float red[256];
    int b = blockIdx.x, t = threadIdx.x;
    s_in[t] = style_in[b * 512 + 256 + t];
    __syncthreads();
    float ss = 0.f;
    for (int i = 0; i < 16; i++) {
        int p = i * 256 + t;
        const float* wr = sp_w + p * SDIM;
        float acc = 0.f;
        for (int k = 0; k < 256; k++) acc += s_in[k] * wr[k];
        float v = acc * LIN_SCALE + sp_b[p];
        sp[b * SPP + p] = v;
        ss += v * v;
    }
    red[t] = ss; __syncthreads();
    for (int o = 128; o > 0; o >>= 1) { if (t < o) red[t] += red[t + o]; __syncthreads(); }
    if (t == 0) dsp[b] = sqrtf((float)SPP / red[0] + EPS);
}

// ---------------- fp32 fallback conv (round-1, known-good) ----------------

#define COTILE 16
#define TS 32
#define HALO 34
#define XS 36

__global__ __launch_bounds__(256) void k_conv_f32(
    const float* __restrict__ x, const float* __restrict__ weight,
    const float* __restrict__ style, const float* __restrict__ demod,
    const float* __restrict__ sp, const float* __restrict__ dsp,
    float* __restrict__ out) {
    __shared__ float xt[HALO * XS];
    __shared__ float wl[COTILE * 12];
    __shared__ float dml[COTILE];

    int bid = blockIdx.x;
    int tile = bid & 3;
    int cot = (bid >> 2) & 15;
    int b = bid >> 6;
    int h0 = (tile >> 1) * TS, w0 = (tile & 1) * TS;
    int t = threadIdx.x;
    int r = t >> 3;
    int cb = (t & 7) * 4;

    if (t < COTILE) dml[t] = demod[b * COUT + cot * COTILE + t];

    float acc[COTILE][4];
#pragma unroll
    for (int co = 0; co < COTILE; co++)
#pragma unroll
        for (int c = 0; c < 4; c++) acc[co][c] = 0.f;

    const float* xb = x + (size_t)b * CIN * SPP;
    const float* stb = style + b * CIN;

    for (int ci = 0; ci < CIN; ci++) {
        __syncthreads();
        const float* xc = xb + ci * SPP;
        for (int idx = t; idx < HALO * HALO; idx += 256) {
            int i = idx / HALO, j = idx - i * HALO;
            int h = h0 + i - 1, wv2 = w0 + j - 1;
            float v = 0.f;
            if ((unsigned)h < SPD && (unsigned)wv2 < SPD) v = xc[h * SPD + wv2];
            xt[i * XS + j] = v;
        }
        if (t < COTILE * 9) {
            int co = t / 9, tap = t - co * 9;
            float wv = weight[((cot * COTILE + co) * CIN + ci) * 9 + tap];
            wl[co * 12 + tap] = wv * (CONV_SCALE * stb[ci]) * dml[co];
        }
        __syncthreads();

        float xv[3][6];
#pragma unroll
        for (int dh = 0; dh < 3; dh++)
#pragma unroll
            for (int jj = 0; jj < 6; jj++)
                xv[dh][jj] = xt[(r + dh) * XS + cb + jj];

#pragma unroll
        for (int co = 0; co < COTILE; co++) {
            float w9[9];
#pragma unroll
            for (int q = 0; q < 9; q++) w9[q] = wl[co * 12 + q];
#pragma unroll
            for (int c = 0; c < 4; c++) {
                float a = acc[co][c];
#pragma unroll
                for (int dh = 0; dh < 3; dh++)
#pragma unroll
                    for (int dw = 0; dw < 3; dw++)
                        a += w9[dh * 3 + dw] * xv[dh][c + dw];
                acc[co][c] = a;
            }
        }
    }

    float dspb = dsp[b];
    int hh = h0 + r, ww = w0 + cb;
    const float* spb = sp + b * SPP + hh * SPD + ww;
    float m[4];
#pragma unroll
    for (int c = 0; c < 4; c++) m[c] = spb[c] * dspb;
#pragma unroll
    for (int co = 0; co < COTILE; co++) {
        float4 v = make_float4(acc[co][0] * m[0], acc[co][1] * m[1],
                               acc[co][2] * m[2], acc[co][3] * m[3]);
        *(float4*)&out[(size_t)((b * COUT + cot * COTILE + co) * SPP) + hh * SPD + ww] = v;
    }
}

// ---------------- launcher ----------------

extern "C" void kernel_launch(void* const* d_in, const int* in_sizes, int n_in,
                              void* d_out, int out_size, void* d_ws, size_t ws_size,
                              hipStream_t stream) {
    const float* x        = (const float*)d_in[0];
    const float* style_in = (const float*)d_in[1];
    const float* weight   = (const float*)d_in[2];
    const float* mod_w    = (const float*)d_in[3];
    const float* mod_b    = (const float*)d_in[4];
    const float* sp_w     = (const float*)d_in[5];
    const float* sp_b     = (const float*)d_in[6];
    float* out = (float*)d_out;
    char* wsb = (char*)d_ws;

    float* style = (float*)(wsb + WSB_STYLE);
    float* demod = (float*)(wsb + WSB_DEMOD);
    float* wsq   = (float*)(wsb + WSB_WSQ);
    float* sp    = (float*)(wsb + WSB_SP);
    float* dsp   = (float*)(wsb + WSB_DSP);
    float* ssqp  = (float*)(wsb + WSB_SSQP);
    unsigned short* wt2 = (unsigned short*)(wsb + WSB_WT2);
    unsigned short* xst = (unsigned short*)(wsb + WSB_XST);

    hipLaunchKernelGGL(k_zero, dim3(1), dim3(256), 0, stream, (unsigned*)(wsb + WSB_ZERO));
    hipLaunchKernelGGL(k_wsq, dim3(COUT), dim3(CIN), 0, stream, weight, wsq);
    hipLaunchKernelGGL(k_style, dim3(BB), dim3(256), 0, stream,
                       style_in, mod_w, mod_b, wsq, style, demod);

    if (ws_size >= WS_NEED) {
        hipLaunchKernelGGL(k_spatial2, dim3(256), dim3(256), 0, stream,
                           style_in, sp_w, sp_b, sp, ssqp);
        hipLaunchKernelGGL(k_dsp, dim3(1), dim3(32), 0, stream, ssqp, dsp);
        hipLaunchKernelGGL(k_wt, dim3(2304), dim3(256), 0, stream, weight, wt2);
        hipLaunchKernelGGL(k_xt, dim3(2048), dim3(256), 0, stream, x, style, xst);
        hipLaunchKernelGGL(k_conv_mfma, dim3(1024), dim3(320), 0, stream,
                           xst, wt2, demod, sp, dsp,
                           (const unsigned short*)(wsb + WSB_ZERO), out);
    } else {
        hipLaunchKernelGGL(k_spatial, dim3(BB), dim3(256), 0, stream,
                           style_in, sp_w, sp_b, sp, dsp);
        hipLaunchKernelGGL(k_conv_f32, dim3(2048), dim3(256), 0, stream,
                           x, weight, style, demod, sp, dsp, out);
    }
}

// Round 10
// 424.078 us; speedup vs baseline: 1.5732x; 1.4348x over previous
//
#include <hip/hip_runtime.h>
#include <math.h>

typedef short short8 __attribute__((ext_vector_type(8)));
typedef float f32x4 __attribute__((ext_vector_type(4)));

#define BB 32
#define CIN 256
#define COUT 256
#define SPD 64
#define SPP 4096
#define SDIM 256

constexpr float LIN_SCALE  = 0.0625f;                 // 1/sqrt(256)
constexpr float CONV_SCALE = 0.020833333333333332f;   // 1/sqrt(2304)
constexpr float EPS = 1e-6f;

// ---- ws byte-offset layout ----
#define WSB_STYLE   0ULL
#define WSB_DEMOD   32768ULL
#define WSB_WSQ     65536ULL
#define WSB_SP      327680ULL
#define WSB_DSP     851968ULL
#define WSB_ZERO    852096ULL      // 1 KiB of zeros
#define WSB_WT2     860160ULL      // 1,179,648 B bf16 weights [tap][co][ci]
#define WSB_SSQP    2039808ULL     // 32,768 B ssq partials [256][32] f32
#define WSB_XST     2097152ULL     // 67,108,864 B bf16 xs_t [b][p][ci]
#define WS_NEED     (WSB_XST + 67108864ULL)

__device__ inline unsigned short f2bf(float f) {
    unsigned u = __builtin_bit_cast(unsigned, f);
    u = (u + 0x7fffu + ((u >> 16) & 1u)) >> 16;   // RNE
    return (unsigned short)u;
}

// async global->LDS DMA, 16B per lane; LDS dest = wave-uniform base + lane*16
__device__ inline void dma16(const void* g, void* l) {
    __builtin_amdgcn_global_load_lds(
        (const __attribute__((address_space(1))) unsigned int*)g,
        (__attribute__((address_space(3))) unsigned int*)l, 16, 0, 0);
}

// ---------------- prep kernels ----------------

__global__ void k_zero(unsigned* __restrict__ p) {
    p[threadIdx.x] = 0u;   // 256 u32 = 1 KiB
}

__global__ void k_wsq(const float* __restrict__ weight, float* __restrict__ wsq) {
    int co = blockIdx.x, ci = threadIdx.x;
    const float* wp = weight + (co * CIN + ci) * 9;
    float s = 0.f;
#pragma unroll
    for (int t = 0; t < 9; t++) { float v = wp[t]; s += v * v; }
    wsq[co * CIN + ci] = s;
}

// style + demod, coalesced: 4 lanes share one row, shfl_xor reduce.
__global__ __launch_bounds__(256) void k_style(
    const float* __restrict__ style_in,
    const float* __restrict__ mod_w,
    const float* __restrict__ mod_b,
    const float* __restrict__ wsq,
    float* __restrict__ style,
    float* __restrict__ demod) {
    __shared__ float s_in[SDIM];
    __shared__ float s2[CIN];
    int b = blockIdx.x, t = threadIdx.x;
    s_in[t] = style_in[b * 512 + t];
    __syncthreads();
    int kq = t & 3, rr = t >> 2;   // rr 0..63
#pragma unroll
    for (int c = 0; c < 4; c++) {
        int ci = c * 64 + rr;
        const float4* wrow = (const float4*)(mod_w + (size_t)ci * 256 + kq * 64);
        float a = 0.f;
#pragma unroll
        for (int j = 0; j < 16; j++) {
            float4 wv = wrow[j];
            int kb = kq * 64 + j * 4;
            a += s_in[kb] * wv.x + s_in[kb + 1] * wv.y + s_in[kb + 2] * wv.z + s_in[kb + 3] * wv.w;
        }
        a += __shfl_xor(a, 1); a += __shfl_xor(a, 2);
        if (kq == 0) {
            float st = a * LIN_SCALE + mod_b[ci];
            style[b * 256 + ci] = st;
            s2[ci] = st * st;
        }
    }
    __syncthreads();
#pragma unroll
    for (int c = 0; c < 4; c++) {
        int co = c * 64 + rr;
        const float4* wrow = (const float4*)(wsq + (size_t)co * 256 + kq * 64);
        float a = 0.f;
#pragma unroll
        for (int j = 0; j < 16; j++) {
            float4 wv = wrow[j];
            int kb = kq * 64 + j * 4;
            a += s2[kb] * wv.x + s2[kb + 1] * wv.y + s2[kb + 2] * wv.z + s2[kb + 3] * wv.w;
        }
        a += __shfl_xor(a, 1); a += __shfl_xor(a, 2);
        if (kq == 0) demod[b * 256 + co] = rsqrtf(CONV_SCALE * CONV_SCALE * a + EPS);
    }
}

// spatial map, parallel: 256 blocks x 16 p-rows; lanes share sp_w rows
// (broadcast); deterministic per-block partial sums (no atomics).
__global__ __launch_bounds__(256) void k_spatial2(
    const float* __restrict__ style_in,
    const float* __restrict__ sp_w,
    const float* __restrict__ sp_b,
    float* __restrict__ sp,
    float* __restrict__ ssq_part) {
    __shared__ float s_in[32][257];
    __shared__ float sred[256];
    int blk = blockIdx.x, t = threadIdx.x;
    int p0 = blk * 16;
    for (int idx = t; idx < 8192; idx += 256) {
        int b = idx >> 8, k = idx & 255;
        s_in[b][k] = style_in[b * 512 + 256 + k];
    }
    __syncthreads();
    int b = t & 31, pl = t >> 5;      // pl 0..7
    float ss = 0.f;
#pragma unroll
    for (int half = 0; half < 2; half++) {
        int p = p0 + half * 8 + pl;
        const float* wr = sp_w + (size_t)p * 256;
        float a = 0.f;
        for (int k = 0; k < 256; k++) a += s_in[b][k] * wr[k];
        float v = a * LIN_SCALE + sp_b[p];
        sp[b * SPP + p] = v;
        ss += v * v;
    }
    sred[t] = ss;
    __syncthreads();
    if (t < 32) {
        float s = 0.f;
#pragma unroll
        for (int r = 0; r < 8; r++) s += sred[r * 32 + t];
        ssq_part[blk * 32 + t] = s;
    }
}

__global__ void k_dsp(const float* __restrict__ ssq_part, float* __restrict__ dsp) {
    int b = threadIdx.x;   // 32 threads
    float s = 0.f;
    for (int i = 0; i < 256; i++) s += ssq_part[i * 32 + b];
    dsp[b] = sqrtf((float)SPP / s + EPS);
}

// weight [co][ci][tap] fp32 -> wt2[tap][co][ci] bf16 (raw, unscaled)
__global__ void k_wt(const float* __restrict__ weight, unsigned short* __restrict__ wt2) {
    int idx = blockIdx.x * 256 + threadIdx.x;   // grid 2304 -> 589824
    int tap = idx >> 16;
    int r = idx & 65535;
    int co = r >> 8, ci = r & 255;
    wt2[idx] = f2bf(weight[(co * 256 + ci) * 9 + tap]);
}

// x [b][ci][p] fp32 -> xs_t[b][p][ci] bf16 scaled by style[b][ci].
// LDS-tiled transpose, coalesced both sides.
__global__ __launch_bounds__(256) void k_xt(
    const float* __restrict__ x, const float* __restrict__ style,
    unsigned short* __restrict__ xst) {
    __shared__ float tile[64][65];
    int bid = blockIdx.x;
    int b  = (bid & 7) * 4 + ((bid >> 3) & 3);
    int p0 = (bid >> 5) * 64;
    int t = threadIdx.x;
    int w = t >> 6, lane = t & 63;
    int hi = t >> 5, lo = t & 31;

    for (int cc = 0; cc < 4; cc++) {
#pragma unroll
        for (int it = 0; it < 16; it++) {
            int ci_l = it * 4 + w;
            int ci = cc * 64 + ci_l;
            float st = style[b * 256 + ci];
            tile[lane][ci_l] = x[((size_t)(b * 256 + ci)) * SPP + p0 + lane] * st;
        }
        __syncthreads();
#pragma unroll
        for (int it = 0; it < 8; it++) {
            int p_l = it * 8 + hi;
            unsigned pk = (unsigned)f2bf(tile[p_l][lo * 2])
                        | ((unsigned)f2bf(tile[p_l][lo * 2 + 1]) << 16);
            unsigned* dst = (unsigned*)xst + ((size_t)(b * SPP + p0 + p_l)) * 128 + cc * 32 + lo;
            *dst = pk;
        }
        __syncthreads();
    }
}

// ---------------- MFMA conv kernel (m=8 co-tiles per wave: LDS-reuse fix) --
// grid 1024: bid -> [rt(5)][b_lo(2)][xcd(3)], b = xcd*4+b_lo, h0 = rt*2
// block 256 = 4 waves; wave w: mw=w&1 -> co half [mw*128, +128), rw=w>>1 ->
// row h0+rw (64 p). Each B-fragment (ds_read_b128) now feeds 8 MFMAs (was 4):
// per-CU LDS demand halves (6912 -> 3456 cyc/kc vs ~2800 MFMA cyc) -- LDS was
// the measured binding pipe at m=4 (MfmaUtil pinned ~22% across r5-r9).
// Staging/swizzle identical to round 6 (measured conflict-clean).

__global__ __launch_bounds__(256, 2) void k_conv_mfma(
    const unsigned short* __restrict__ xst,
    const unsigned short* __restrict__ wt2,
    const float* __restrict__ demod,
    const float* __restrict__ sp,
    const float* __restrict__ dsp,
    const unsigned short* __restrict__ zeropad,
    float* __restrict__ out)
{
    __shared__ union {
        char stage[2][16896];      // 2 x 264 slots x 64B
        float ep[4][2176];         // 4 waves x 32 rows x 68 floats (34816 B)
    } lds;
    __shared__ float demod_l[256];

    int bid = blockIdx.x;
    int b  = (bid & 7) * 4 + ((bid >> 3) & 3);
    int rt = bid >> 5;
    int h0 = rt * 2;
    int t = threadIdx.x;
    int w = t >> 6, lane = t & 63;
    int mw = w & 1, rw = w >> 1;
    int lcol = lane & 15, kg = lane >> 4;

    demod_l[t] = demod[b * 256 + t];

    const unsigned short* xb = xst + (size_t)b * SPP * 256;

    // per-thread DMA source pointers (kc advances source by 32 elements)
    const unsigned short* sbase[5];
#pragma unroll
    for (int it = 0; it < 5; it++) {
        int idx16 = t + it * 256;
        const unsigned short* s = zeropad;
        if (idx16 < 1056) {
            int slot = idx16 >> 2, j = idx16 & 3;
            int row = slot / 66, col = slot - row * 66;
            int g = j ^ ((slot >> 1) & 3);     // inverse swizzle on source
            int gh = h0 + row - 1, gw = col - 1;
            if ((unsigned)gh < 64u && (unsigned)gw < 64u)
                s = xb + ((size_t)(gh * 64 + gw)) * 256 + g * 8;
        }
        sbase[it] = s;
    }

#define STAGE_DMA(BUF, KC) { _Pragma("unroll") \
    for (int it = 0; it < 4; it++) \
        dma16(sbase[it] + (KC) * 32, &lds.stage[BUF][0] + (t + it * 256) * 16); \
    if (t < 32) dma16(sbase[4] + (KC) * 32, &lds.stage[BUF][0] + (t + 1024) * 16); }

    STAGE_DMA(0, 0);

    f32x4 acc[8][4];
#pragma unroll
    for (int m = 0; m < 8; m++)
#pragma unroll
        for (int n = 0; n < 4; n++) acc[m][n] = (f32x4){0.f, 0.f, 0.f, 0.f};

    const unsigned short* wbase = wt2 + (size_t)(mw * 128 + lcol) * 256 + kg * 8;
    int cur = 0;
    __syncthreads();   // drain prologue DMA

    for (int kc = 0; kc < 8; kc++) {
        if (kc < 7) STAGE_DMA(cur ^ 1, kc + 1);
        const char* lb = &lds.stage[cur][0];
        const unsigned short* wk = wbase + kc * 32;

#pragma unroll
        for (int tap = 0; tap < 9; tap++) {
            const int dh = tap / 3, dw = tap - dh * 3;
            const unsigned short* wt_ = wk + tap * 65536;
            short8 wA[8];
#pragma unroll
            for (int m = 0; m < 8; m++) wA[m] = *(const short8*)(wt_ + m * 4096);
            int sbase0 = (rw + dh) * 66 + dw + lcol;
            int q = (sbase0 >> 1) & 3;               // n*16 doesn't touch bits 1-2
            const char* lbp = lb + sbase0 * 64 + ((kg ^ q) << 4);
#pragma unroll
            for (int n = 0; n < 4; n++) {
                short8 bv = *(const short8*)(lbp + n * 1024);
#pragma unroll
                for (int m = 0; m < 8; m++)
                    acc[m][n] = __builtin_amdgcn_mfma_f32_16x16x32_bf16(wA[m], bv, acc[m][n], 0, 0, 0);
            }
        }

        __syncthreads();
        cur ^= 1;
    }

    // ---- epilogue: scale, per-wave LDS transpose, coalesced dwordx4 stores ----
    // Each wave uses its private ep region; within-wave LDS ordering is
    // handled by lgkmcnt -> no barriers needed here (kc loop's final
    // __syncthreads already fenced the stage-buffer reuse).
    float dspb = dsp[b];
    int hout = h0 + rw;
    float spn[4];
#pragma unroll
    for (int nn = 0; nn < 4; nn++)
        spn[nn] = sp[b * SPP + hout * 64 + nn * 16 + lcol] * dspb;

    float* ep = &lds.ep[w][0];
#pragma unroll
    for (int ch = 0; ch < 4; ch++) {          // 4 chunks of 32 co
#pragma unroll
        for (int mm = 0; mm < 2; mm++) {
#pragma unroll
            for (int r2 = 0; r2 < 4; r2++) {
                int lr = mm * 16 + kg * 4 + r2;
                float dm = demod_l[mw * 128 + ch * 32 + lr] * CONV_SCALE;
#pragma unroll
                for (int nn = 0; nn < 4; nn++)
                    ep[lr * 68 + nn * 16 + lcol] =
                        acc[ch * 2 + mm][nn][r2] * dm * spn[nn];
            }
        }
#pragma unroll
        for (int i = 0; i < 8; i++) {
            int lr = i * 4 + kg;
            f32x4 v = *(const f32x4*)(ep + lr * 68 + lcol * 4);
            int co_g = mw * 128 + ch * 32 + lr;
            *(f32x4*)&out[((size_t)(b * 256 + co_g)) * SPP + hout * 64 + lcol * 4] = v;
        }
    }
}

// ---------------- legacy spatial (fallback path only) ----------------
__global__ void k_spatial(const float* __restrict__ style_in,
                          const float* __restrict__ sp_w,
                          const float* __restrict__ sp_b,
                          float* __restrict__ sp,
                          float* __restrict__ dsp) {
    __shared__ float s_in[SDIM];
    __shared__ float red[256];
    int b = blockIdx.x, t = threadIdx.x;
    s_in[t] = style_in[b * 512 + 256 + t];
    __syncthreads();
    float ss = 0.f;
    for (int i = 0; i < 16; i++) {
        int p = i * 256 + t;
        const float* wr = sp_w + p * SDIM;
        float acc = 0.f;
        for (int k = 0; k < 256; k++) acc += s_in[k] * wr[k];
        float v = acc * LIN_SCALE + sp_b[p];
        sp[b * SPP + p] = v;
        ss += v * v;
    }
    red[t] = ss; __syncthreads();
    for (int o = 128; o > 0; o >>= 1) { if (t < o) red[t] += red[t + o]; __syncthreads(); }
    if (t == 0) dsp[b] = sqrtf((float)SPP / red[0] + EPS);
}

// ---------------- fp32 fallback conv (round-1, known-good) ----------------

#define COTILE 16
#define TS 32
#define HALO 34
#define XS 36

__global__ __launch_bounds__(256) void k_conv_f32(
    const float* __restrict__ x, const float* __restrict__ weight,
    const float* __restrict__ style, const float* __restrict__ demod,
    const float* __restrict__ sp, const float* __restrict__ dsp,
    float* __restrict__ out) {
    __shared__ float xt[HALO * XS];
    __shared__ float wl[COTILE * 12];
    __shared__ float dml[COTILE];

    int bid = blockIdx.x;
    int tile = bid & 3;
    int cot = (bid >> 2) & 15;
    int b = bid >> 6;
    int h0 = (tile >> 1) * TS, w0 = (tile & 1) * TS;
    int t = threadIdx.x;
    int r = t >> 3;
    int cb = (t & 7) * 4;

    if (t < COTILE) dml[t] = demod[b * COUT + cot * COTILE + t];

    float acc[COTILE][4];
#pragma unroll
    for (int co = 0; co < COTILE; co++)
#pragma unroll
        for (int c = 0; c < 4; c++) acc[co][c] = 0.f;

    const float* xb = x + (size_t)b * CIN * SPP;
    const float* stb = style + b * CIN;

    for (int ci = 0; ci < CIN; ci++) {
        __syncthreads();
        const float* xc = xb + ci * SPP;
        for (int idx = t; idx < HALO * HALO; idx += 256) {
            int i = idx / HALO, j = idx - i * HALO;
            int h = h0 + i - 1, wv2 = w0 + j - 1;
            float v = 0.f;
            if ((unsigned)h < SPD && (unsigned)wv2 < SPD) v = xc[h * SPD + wv2];
            xt[i * XS + j] = v;
        }
        if (t < COTILE * 9) {
            int co = t / 9, tap = t - co * 9;
            float wv = weight[((cot * COTILE + co) * CIN + ci) * 9 + tap];
            wl[co * 12 + tap] = wv * (CONV_SCALE * stb[ci]) * dml[co];
        }
        __syncthreads();

        float xv[3][6];
#pragma unroll
        for (int dh = 0; dh < 3; dh++)
#pragma unroll
            for (int jj = 0; jj < 6; jj++)
                xv[dh][jj] = xt[(r + dh) * XS + cb + jj];

#pragma unroll
        for (int co = 0; co < COTILE; co++) {
            float w9[9];
#pragma unroll
            for (int q = 0; q < 9; q++) w9[q] = wl[co * 12 + q];
#pragma unroll
            for (int c = 0; c < 4; c++) {
                float a = acc[co][c];
#pragma unroll
                for (int dh = 0; dh < 3; dh++)
#pragma unroll
                    for (int dw = 0; dw < 3; dw++)
                        a += w9[dh * 3 + dw] * xv[dh][c + dw];
                acc[co][c] = a;
            }
        }
    }

    float dspb = dsp[b];
    int hh = h0 + r, ww = w0 + cb;
    const float* spb = sp + b * SPP + hh * SPD + ww;
    float m[4];
#pragma unroll
    for (int c = 0; c < 4; c++) m[c] = spb[c] * dspb;
#pragma unroll
    for (int co = 0; co < COTILE; co++) {
        float4 v = make_float4(acc[co][0] * m[0], acc[co][1] * m[1],
                               acc[co][2] * m[2], acc[co][3] * m[3]);
        *(float4*)&out[(size_t)((b * COUT + cot * COTILE + co) * SPP) + hh * SPD + ww] = v;
    }
}

// ---------------- launcher ----------------

extern "C" void kernel_launch(void* const* d_in, const int* in_sizes, int n_in,
                              void* d_out, int out_size, void* d_ws, size_t ws_size,
                              hipStream_t stream) {
    const float* x        = (const float*)d_in[0];
    const float* style_in = (const float*)d_in[1];
    const float* weight   = (const float*)d_in[2];
    const float* mod_w    = (const float*)d_in[3];
    const float* mod_b    = (const float*)d_in[4];
    const float* sp_w     = (const float*)d_in[5];
    const float* sp_b     = (const float*)d_in[6];
    float* out = (float*)d_out;
    char* wsb = (char*)d_ws;

    float* style = (float*)(wsb + WSB_STYLE);
    float* demod = (float*)(wsb + WSB_DEMOD);
    float* wsq   = (float*)(wsb + WSB_WSQ);
    float* sp    = (float*)(wsb + WSB_SP);
    float* dsp   = (float*)(wsb + WSB_DSP);
    float* ssqp  = (float*)(wsb + WSB_SSQP);
    unsigned short* wt2 = (unsigned short*)(wsb + WSB_WT2);
    unsigned short* xst = (unsigned short*)(wsb + WSB_XST);

    hipLaunchKernelGGL(k_zero, dim3(1), dim3(256), 0, stream, (unsigned*)(wsb + WSB_ZERO));
    hipLaunchKernelGGL(k_wsq, dim3(COUT), dim3(CIN), 0, stream, weight, wsq);
    hipLaunchKernelGGL(k_style, dim3(BB), dim3(256), 0, stream,
                       style_in, mod_w, mod_b, wsq, style, demod);

    if (ws_size >= WS_NEED) {
        hipLaunchKernelGGL(k_spatial2, dim3(256), dim3(256), 0, stream,
                           style_in, sp_w, sp_b, sp, ssqp);
        hipLaunchKernelGGL(k_dsp, dim3(1), dim3(32), 0, stream, ssqp, dsp);
        hipLaunchKernelGGL(k_wt, dim3(2304), dim3(256), 0, stream, weight, wt2);
        hipLaunchKernelGGL(k_xt, dim3(2048), dim3(256), 0, stream, x, style, xst);
        hipLaunchKernelGGL(k_conv_mfma, dim3(1024), dim3(256), 0, stream,
                           xst, wt2, demod, sp, dsp,
                           (const unsigned short*)(wsb + WSB_ZERO), out);
    } else {
        hipLaunchKernelGGL(k_spatial, dim3(BB), dim3(256), 0, stream,
                           style_in, sp_w, sp_b, sp, dsp);
        hipLaunchKernelGGL(k_conv_f32, dim3(2048), dim3(256), 0, stream,
                           x, weight, style, demod, sp, dsp, out);
    }
}